// Round 3
// baseline (734.322 us; speedup 1.0000x reference)
//
#include <hip/hip_runtime.h>

#define SEQ 2048
#define BATCH 32
#define HID 1024
#define SPW 8  // s-rows per wave in score kernel

// Kernel 1: v[b,h] = sum_k hidden[b,k] * W[k,h]   (v = hidden @ W)
// Split-K: grid (b, hc) = (32, 8) = 256 blocks (one per CU).
// Also zeroes the fan-in counters for kernel 2 on the true first launch
// (d_ws is poisoned between iterations; kernel-boundary coherence makes
// the zeros visible to kernel 2).
__global__ void __launch_bounds__(256) vproj_kernel(const float* __restrict__ hidden,
                                                    const float* __restrict__ W,
                                                    float* __restrict__ v,
                                                    unsigned* __restrict__ counters) {
    const int b  = blockIdx.x;
    const int hc = blockIdx.y;
    const int t  = threadIdx.x;
    const int h4 = hc * 32 + (t & 31);
    const int kk = t >> 5;

    if (b == 0 && hc == 0 && t < 8) counters[t] = 0u;

    __shared__ float  sh[HID];
    __shared__ float4 red[256];

    // stage hidden row
    ((float4*)sh)[t] = ((const float4*)(hidden + b * HID))[t];
    __syncthreads();

    const float4* __restrict__ W4 = (const float4*)W;  // [HID][HID/4]
    float4 acc = make_float4(0.f, 0.f, 0.f, 0.f);
    const int k0 = kk * 128;
#pragma unroll 8
    for (int k = k0; k < k0 + 128; ++k) {
        const float  hk = sh[k];
        const float4 w  = W4[k * (HID / 4) + h4];  // 512B contiguous per 32 lanes
        acc.x = fmaf(hk, w.x, acc.x);
        acc.y = fmaf(hk, w.y, acc.y);
        acc.z = fmaf(hk, w.z, acc.z);
        acc.w = fmaf(hk, w.w, acc.w);
    }

    // reduce over kk (stride 32 in red[])
    red[t] = acc;
    __syncthreads();
    if (t < 128) {
        float4 a = red[t], c = red[t + 128];
        a.x += c.x; a.y += c.y; a.z += c.z; a.w += c.w;
        red[t] = a;
    }
    __syncthreads();
    if (t < 64) {
        float4 a = red[t], c = red[t + 64];
        a.x += c.x; a.y += c.y; a.z += c.z; a.w += c.w;
        red[t] = a;
    }
    __syncthreads();
    if (t < 32) {
        float4 a = red[t], c = red[t + 32];
        a.x += c.x; a.y += c.y; a.z += c.z; a.w += c.w;
        ((float4*)v)[b * (HID / 4) + hc * 32 + t] = a;
    }
}

// Kernel 2 (fused): scores[b,s] = enc[s,b,:] . v[b,:], then softmax over s.
// Streaming phase: grid (SEQ/SPW, BATCH/4) = (256, 8) = 2048 blocks. Each
// wave owns one b, holds v[b] in 16 VGPRs, streams SPW=8 consecutive s-rows
// (coalesced float4); enc read exactly once -> HBM floor.
// Fan-in phase: per y-group counter; the 256th block to arrive runs the
// softmax for its 4 batch rows (wave w handles b = 4*y + w; 2048/64 = 32
// values per lane, wave-local shfl reduction). The last block RESETS the
// counter before the softmax, so the kernel is idempotent across rocprof
// dispatch replays (which re-run this kernel without re-running vproj).
// No spin anywhere -> no deadlock regardless of residency.
__global__ void __launch_bounds__(256, 4) score_softmax_kernel(
        const float* __restrict__ enc, const float* __restrict__ v,
        float* __restrict__ scores, unsigned* __restrict__ counters) {
    const int sx   = blockIdx.x;           // s-chunk
    const int wave = threadIdx.x >> 6;
    const int lane = threadIdx.x & 63;
    const int b    = blockIdx.y * 4 + wave;

    const float4* __restrict__ v4 = (const float4*)(v + b * HID);
    const float4 w0 = v4[0 * 64 + lane];
    const float4 w1 = v4[1 * 64 + lane];
    const float4 w2 = v4[2 * 64 + lane];
    const float4 w3 = v4[3 * 64 + lane];

    const int s0 = sx * SPW;
#pragma unroll 1
    for (int i = 0; i < SPW; ++i) {
        const int s = s0 + i;
        const float4* __restrict__ e4 =
            (const float4*)(enc + ((size_t)s * BATCH + b) * HID);
        const float4 e0 = e4[0 * 64 + lane];  // coalesced 16B/lane, 1KB/instr
        const float4 e1 = e4[1 * 64 + lane];
        const float4 e2 = e4[2 * 64 + lane];
        const float4 e3 = e4[3 * 64 + lane];

        float acc = 0.f;
        acc = fmaf(e0.x, w0.x, acc); acc = fmaf(e0.y, w0.y, acc);
        acc = fmaf(e0.z, w0.z, acc); acc = fmaf(e0.w, w0.w, acc);
        acc = fmaf(e1.x, w1.x, acc); acc = fmaf(e1.y, w1.y, acc);
        acc = fmaf(e1.z, w1.z, acc); acc = fmaf(e1.w, w1.w, acc);
        acc = fmaf(e2.x, w2.x, acc); acc = fmaf(e2.y, w2.y, acc);
        acc = fmaf(e2.z, w2.z, acc); acc = fmaf(e2.w, w2.w, acc);
        acc = fmaf(e3.x, w3.x, acc); acc = fmaf(e3.y, w3.y, acc);
        acc = fmaf(e3.z, w3.z, acc); acc = fmaf(e3.w, w3.w, acc);

#pragma unroll
        for (int off = 32; off > 0; off >>= 1) acc += __shfl_xor(acc, off, 64);
        if (lane == 0) scores[b * SEQ + s] = acc;
    }

    // ---- fan-in: last block of this y-group runs the softmax ----
    __syncthreads();                 // all waves of this block done writing
    __threadfence();                 // release: scores visible device-wide
    __shared__ unsigned last;
    if (threadIdx.x == 0) last = atomicAdd(&counters[blockIdx.y], 1u);
    __syncthreads();
    if (last != (SEQ / SPW) - 1) return;   // not the last block for this y
    __threadfence();                 // acquire: see all other blocks' scores
    if (threadIdx.x == 0) counters[blockIdx.y] = 0u;  // re-arm for replay

    // wave `wave` owns row b = blockIdx.y*4 + wave; 32 values per lane.
    float x[32];
    float m = -INFINITY;
#pragma unroll
    for (int j = 0; j < 32; ++j) {
        x[j] = scores[b * SEQ + j * 64 + lane];
        m = fmaxf(m, x[j]);
    }
#pragma unroll
    for (int off = 32; off > 0; off >>= 1) m = fmaxf(m, __shfl_xor(m, off, 64));

    float sum = 0.f;
#pragma unroll
    for (int j = 0; j < 32; ++j) {
        x[j] = __expf(x[j] - m);
        sum += x[j];
    }
#pragma unroll
    for (int off = 32; off > 0; off >>= 1) sum += __shfl_xor(sum, off, 64);
    const float inv = 1.f / sum;
#pragma unroll
    for (int j = 0; j < 32; ++j) scores[b * SEQ + j * 64 + lane] = x[j] * inv;
}

extern "C" void kernel_launch(void* const* d_in, const int* in_sizes, int n_in,
                              void* d_out, int out_size, void* d_ws, size_t ws_size,
                              hipStream_t stream) {
    const float* hidden = (const float*)d_in[0];  // [B,H]
    const float* enc    = (const float*)d_in[1];  // [S,B,H]
    const float* W      = (const float*)d_in[2];  // [H,H]
    // d_in[3] = bias: constant over s per b -> cancels in softmax; unused.
    float* out = (float*)d_out;                   // [1,B,S] fp32

    float* v           = (float*)d_ws;            // B*H floats (128 KB)
    unsigned* counters = (unsigned*)(v + BATCH * HID);  // 8 fan-in counters
    float* scores      = out;                     // staged + softmaxed in d_out

    vproj_kernel<<<dim3(BATCH, 8), 256, 0, stream>>>(hidden, W, v, counters);
    score_softmax_kernel<<<dim3(SEQ / SPW, BATCH / 4), 256, 0, stream>>>(
        enc, v, scores, counters);
}

// Round 4
// 378.633 us; speedup vs baseline: 1.9394x; 1.9394x over previous
//
#include <hip/hip_runtime.h>

#define SEQ 2048
#define BATCH 32
#define HID 1024

// Kernel 1: v[b,h] = sum_k hidden[b,k] * W[k,h]   (v = hidden @ W)
// Split-K: grid (b, hc) = (32, 8) = 256 blocks (one per CU).
// Block (b,hc) owns h4 columns [hc*32, hc*32+32) (float4 units = 128 floats).
// Thread t: h4 = hc*32 + (t&31), K-strip kk = t>>5 (8 strips x 128 k).
// LDS tree-reduce over the 8 K-strips at the end.
__global__ void __launch_bounds__(256) vproj_kernel(const float* __restrict__ hidden,
                                                    const float* __restrict__ W,
                                                    float* __restrict__ v) {
    const int b  = blockIdx.x;
    const int hc = blockIdx.y;
    const int t  = threadIdx.x;
    const int h4 = hc * 32 + (t & 31);
    const int kk = t >> 5;

    __shared__ float  sh[HID];
    __shared__ float4 red[256];

    // stage hidden row
    ((float4*)sh)[t] = ((const float4*)(hidden + b * HID))[t];
    __syncthreads();

    const float4* __restrict__ W4 = (const float4*)W;  // [HID][HID/4]
    float4 acc = make_float4(0.f, 0.f, 0.f, 0.f);
    const int k0 = kk * 128;
#pragma unroll 8
    for (int k = k0; k < k0 + 128; ++k) {
        const float  hk = sh[k];
        const float4 w  = W4[k * (HID / 4) + h4];  // 512B contiguous per 32 lanes
        acc.x = fmaf(hk, w.x, acc.x);
        acc.y = fmaf(hk, w.y, acc.y);
        acc.z = fmaf(hk, w.z, acc.z);
        acc.w = fmaf(hk, w.w, acc.w);
    }

    // reduce over kk (stride 32 in red[])
    red[t] = acc;
    __syncthreads();
    if (t < 128) {
        float4 a = red[t], c = red[t + 128];
        a.x += c.x; a.y += c.y; a.z += c.z; a.w += c.w;
        red[t] = a;
    }
    __syncthreads();
    if (t < 64) {
        float4 a = red[t], c = red[t + 64];
        a.x += c.x; a.y += c.y; a.z += c.z; a.w += c.w;
        red[t] = a;
    }
    __syncthreads();
    if (t < 32) {
        float4 a = red[t], c = red[t + 32];
        a.x += c.x; a.y += c.y; a.z += c.z; a.w += c.w;
        ((float4*)v)[b * (HID / 4) + hc * 32 + t] = a;
    }
}

// Kernel 2: scores[b,s] = enc[s,b,:] . v[b,:]
// One wave per (s,b). Block = 4 waves = 4 consecutive b at the same s
// (contiguous 16 KB of enc per block). enc read exactly once -> HBM floor
// (round-3 profile: ~half of enc is L3-resident between iterations, so the
// stream runs above nominal HBM rate). NO cross-block sync anywhere:
// round-3 showed per-block agent-scope fences (L2 wb/inv on 8 XCDs) cost
// ~400 us -- kernel boundaries are the cheap sync here.
__global__ void __launch_bounds__(256) score_kernel(const float* __restrict__ enc,
                                                    const float* __restrict__ v,
                                                    float* __restrict__ scores) {
    const int s = blockIdx.x;
    const int wave = threadIdx.x >> 6;
    const int lane = threadIdx.x & 63;
    const int b = blockIdx.y * 4 + wave;

    const float4* __restrict__ e4 = (const float4*)(enc + ((size_t)s * BATCH + b) * HID);
    const float4* __restrict__ v4 = (const float4*)(v + b * HID);

    float acc = 0.f;
#pragma unroll
    for (int j = 0; j < 4; ++j) {
        const float4 e = e4[j * 64 + lane];  // coalesced 16B/lane
        const float4 w = v4[j * 64 + lane];  // 4KB working set/b -> cache-resident
        acc = fmaf(e.x, w.x, acc);
        acc = fmaf(e.y, w.y, acc);
        acc = fmaf(e.z, w.z, acc);
        acc = fmaf(e.w, w.w, acc);
    }
#pragma unroll
    for (int off = 32; off > 0; off >>= 1) acc += __shfl_xor(acc, off, 64);
    if (lane == 0) scores[b * SEQ + s] = acc;
}

// Kernel 3: out[b,s] = softmax_s(scores[b,:]). One block per b.
__global__ void __launch_bounds__(256) softmax_kernel(const float* __restrict__ scores,
                                                      float* __restrict__ out) {
    const int b = blockIdx.x;
    const int t = threadIdx.x;
    __shared__ float red[256];

    float x[8];
    float m = -INFINITY;
#pragma unroll
    for (int j = 0; j < 8; ++j) {
        x[j] = scores[b * SEQ + t + j * 256];
        m = fmaxf(m, x[j]);
    }
    red[t] = m;
    __syncthreads();
    for (int o = 128; o > 0; o >>= 1) {
        if (t < o) red[t] = fmaxf(red[t], red[t + o]);
        __syncthreads();
    }
    m = red[0];
    __syncthreads();

    float sum = 0.f;
#pragma unroll
    for (int j = 0; j < 8; ++j) {
        x[j] = __expf(x[j] - m);
        sum += x[j];
    }
    red[t] = sum;
    __syncthreads();
    for (int o = 128; o > 0; o >>= 1) {
        if (t < o) red[t] += red[t + o];
        __syncthreads();
    }
    const float inv = 1.f / red[0];
#pragma unroll
    for (int j = 0; j < 8; ++j) out[b * SEQ + t + j * 256] = x[j] * inv;
}

extern "C" void kernel_launch(void* const* d_in, const int* in_sizes, int n_in,
                              void* d_out, int out_size, void* d_ws, size_t ws_size,
                              hipStream_t stream) {
    const float* hidden = (const float*)d_in[0];  // [B,H]
    const float* enc    = (const float*)d_in[1];  // [S,B,H]
    const float* W      = (const float*)d_in[2];  // [H,H]
    // d_in[3] = bias: constant over s per b -> cancels in softmax; unused.
    float* out = (float*)d_out;                   // [1,B,S] fp32

    float* v      = (float*)d_ws;                 // B*H   floats (128 KB)
    float* scores = v + BATCH * HID;              // B*S   floats (256 KB)

    vproj_kernel<<<dim3(BATCH, 8), 256, 0, stream>>>(hidden, W, v);
    score_kernel<<<dim3(SEQ, BATCH / 4), 256, 0, stream>>>(enc, v, scores);
    softmax_kernel<<<BATCH, 256, 0, stream>>>(scores, out);
}